// Round 3
// baseline (500.280 us; speedup 1.0000x reference)
//
#include <hip/hip_runtime.h>

// LIF layer: T=16, B=32, C=128, H=32, W=32, float32 in/out.
// v = v*0.5 + I[t]; spike = (v >= 1.0); v -= spike  (subtract reset)
//
// Round-2 lesson: 1-deep prefetch still serializes ~16 HBM latencies per
// wave (compute per step ~100cy << 900cy load latency). T=16 is small:
// load the WHOLE per-neuron time series into registers first (16 float4 =
// 64 VGPR), so each wave exposes ~one load latency total, then compute+store.
// G=1 keeps grid at 4096 blocks (full occupancy, ~24 waves/CU at ~80 VGPR).

constexpr int T_STEPS = 16;
constexpr int N_NEUR  = 32 * 128 * 32 * 32;   // 4,194,304 per time step
constexpr int N4      = N_NEUR / 4;           // 1,048,576 float4 / step
constexpr int BLK     = 256;
constexpr float DECAY = 0.5f;
constexpr float THR   = 1.0f;

typedef float f32x4 __attribute__((ext_vector_type(4)));

__global__ __launch_bounds__(BLK) void lif_fwd(const f32x4* __restrict__ x,
                                               f32x4* __restrict__ out) {
    const int i = blockIdx.x * BLK + threadIdx.x;   // [0, N4)

    // Phase 1: issue all 16 independent loads (16 KiB/wave in flight).
    f32x4 c[T_STEPS];
#pragma unroll
    for (int t = 0; t < T_STEPS; ++t) {
        c[t] = x[(size_t)t * N4 + i];
    }

    // Phase 2: serial LIF recurrence, one progressive vmcnt wait per step.
    f32x4 v = {0.f, 0.f, 0.f, 0.f};
#pragma unroll
    for (int t = 0; t < T_STEPS; ++t) {
        v.x = v.x * DECAY + c[t].x;
        v.y = v.y * DECAY + c[t].y;
        v.z = v.z * DECAY + c[t].z;
        v.w = v.w * DECAY + c[t].w;
        f32x4 s;
        s.x = (v.x >= THR) ? 1.0f : 0.0f;
        s.y = (v.y >= THR) ? 1.0f : 0.0f;
        s.z = (v.z >= THR) ? 1.0f : 0.0f;
        s.w = (v.w >= THR) ? 1.0f : 0.0f;
        v.x -= s.x;
        v.y -= s.y;
        v.z -= s.z;
        v.w -= s.w;
        __builtin_nontemporal_store(s, &out[(size_t)t * N4 + i]);
    }
}

extern "C" void kernel_launch(void* const* d_in, const int* in_sizes, int n_in,
                              void* d_out, int out_size, void* d_ws, size_t ws_size,
                              hipStream_t stream) {
    const f32x4* x = (const f32x4*)d_in[0];
    f32x4* out = (f32x4*)d_out;
    lif_fwd<<<dim3(N4 / BLK), dim3(BLK), 0, stream>>>(x, out);
}